// Round 11
// baseline (411.733 us; speedup 1.0000x reference)
//
#include <hip/hip_runtime.h>

#define NN 50000      // nodes
#define NP1 (NN + 1)  // +1 virtual zero row for even-padding
#define NE 800000     // edges
#define FD 128        // input feature dim
#define HD 256        // hidden dim
#define AD 32         // action dim
#define GN 50         // graphs
#define BN_EPS 1e-5f

#define EPI_STATS 0
#define EPI_POOL  1

typedef float f32x4 __attribute__((ext_vector_type(4)));
typedef short s16x8 __attribute__((ext_vector_type(8)));

__device__ inline unsigned short f2bf(float f) {
    unsigned u = __float_as_uint(f);
    u += 0x7FFF + ((u >> 16) & 1);   // round-to-nearest-even
    return (unsigned short)(u >> 16);
}
__device__ inline float bflo(unsigned u) { return __uint_as_float(u << 16); }
__device__ inline float bfhi(unsigned u) { return __uint_as_float(u & 0xffff0000u); }

// ---------------- degree / CSR build ----------------

__global__ void k_deg(const int* __restrict__ dst, int* __restrict__ counts) {
    int e = blockIdx.x * blockDim.x + threadIdx.x;
    if (e < NE) atomicAdd(&counts[dst[e]], 1);
}

__global__ void k_dis(const int* __restrict__ counts, float* __restrict__ dis) {
    int i = blockIdx.x * blockDim.x + threadIdx.x;
    if (i < NN) dis[i] = rsqrtf(1.0f + (float)counts[i]);
    if (i == 0) dis[NN] = 0.0f;
}

__global__ void k_scan1(const int* __restrict__ counts, int* __restrict__ rowptr,
                        int* __restrict__ bsum) {
    __shared__ int s[1024];
    int t = threadIdx.x;
    int i = blockIdx.x * 1024 + t;
    int v = (i < NN) ? ((counts[i] + 1) & ~1) : 0;
    s[t] = v;
    __syncthreads();
    for (int off = 1; off < 1024; off <<= 1) {
        int u = (t >= off) ? s[t - off] : 0;
        __syncthreads();
        s[t] += u;
        __syncthreads();
    }
    if (i < NN) rowptr[i + 1] = s[t];
    if (t == 1023) bsum[blockIdx.x] = s[1023];
}

__global__ void k_scan2(int* __restrict__ bsum, int* __restrict__ rowptr, int nblk) {
    if (threadIdx.x == 0 && blockIdx.x == 0) {
        int run = 0;
        for (int b = 0; b < nblk; ++b) { int t = bsum[b]; bsum[b] = run; run += t; }
        rowptr[0] = 0;
    }
}

__global__ void k_scan3(int* __restrict__ rowptr, const int* __restrict__ bsum) {
    int i = blockIdx.x * blockDim.x + threadIdx.x;
    if (i < NN) rowptr[i + 1] += bsum[i >> 10];
}

__global__ void k_csr(const int* __restrict__ src, const int* __restrict__ dst,
                      const int* __restrict__ rowptr, int* __restrict__ fill,
                      unsigned short* __restrict__ csru) {
    int e = blockIdx.x * blockDim.x + threadIdx.x;
    if (e < NE) {
        int d = dst[e];
        int p = rowptr[d] + atomicAdd(&fill[d], 1);
        csru[p] = (unsigned short)src[e];
    }
}

__global__ void k_pad(const int* __restrict__ counts, const int* __restrict__ rowptr,
                      unsigned short* __restrict__ csru) {
    int n = blockIdx.x * 256 + threadIdx.x;
    if (n < NN) {
        int c = counts[n];
        if (c & 1) csru[rowptr[n] + c] = (unsigned short)NN;
    }
}

__global__ void k_dsum(const int* __restrict__ rowptr, const unsigned short* __restrict__ csru,
                       const float* __restrict__ dis, float* __restrict__ dsum) {
    int n = blockIdx.x * 256 + threadIdx.x;
    if (n < NN) {
        float s = dis[n];
        int e1 = rowptr[n + 1];
        for (int e = rowptr[n]; e < e1; ++e) s += dis[csru[e]];
        dsum[n] = s;
    }
}

// ---------------- casts ----------------

__global__ void k_castW(const float* __restrict__ W, unsigned short* __restrict__ Wt, int K) {
    int idx = blockIdx.x * 256 + threadIdx.x;
    if (idx < K * HD) {
        int c = idx / K, k = idx - c * K;
        Wt[idx] = f2bf(W[(size_t)k * HD + c]);
    }
}

__global__ void k_castx(const float* __restrict__ x, const float* __restrict__ dis,
                        unsigned* __restrict__ xb) {
    int idx = blockIdx.x * 256 + threadIdx.x;
    if (idx < NN * (FD / 2)) {
        int n = idx >> 6, jj = idx & 63;
        int chunk = jj >> 4, w = jj & 15;
        float sc = dis[n];
        float2 v = *(const float2*)&x[(size_t)n * FD + jj * 2];
        xb[((size_t)chunk * NP1 + n) * 16 + w] =
            ((unsigned)f2bf(v.y * sc) << 16) | f2bf(v.x * sc);
    }
}

__global__ void k_zrow(unsigned* __restrict__ xb, unsigned* __restrict__ tbuf) {
    int t = threadIdx.x;    // 192 threads
    if (t < 64) xb[((size_t)(t >> 4) * NP1 + NN) * 16 + (t & 15)] = 0;
    else if (t < 192) {
        int q = t - 64;
        tbuf[((size_t)(q >> 4) * NP1 + NN) * 16 + (q & 15)] = 0;
    }
}

// ---------------- MFMA bf16 GEMM, 128x128 tile, double-buffered staging ----------------
// A chunked bf16-packed [K/32][NP1][16 uints]; Wt bf16 [HD][K].
// grid = numRowTiles*2; bit0 = column half (colBase 0/128).
// EPI_STATS: Cout = dis*relu(acc+bias) chunked bf16 + stats8 partial sums.
// EPI_POOL : boundary-aware fused graph mean-pool (sums into pooled).

template<int K, int EPI>
__global__ __launch_bounds__(256) void k_mm2(const unsigned* __restrict__ Ab,
                                             const unsigned short* __restrict__ Wt,
                                             const float* __restrict__ bias,
                                             const float* __restrict__ dis,
                                             unsigned short* __restrict__ Cout,
                                             float* __restrict__ stats8,
                                             const int* __restrict__ batch,
                                             const int* __restrict__ gstart,
                                             float* __restrict__ pooled) {
    __shared__ __align__(16) short Als[2][128 * 40];   // 20 KB
    __shared__ __align__(16) short Bls[2][128 * 40];   // 20 KB
    int t = threadIdx.x;
    int rowBase = (blockIdx.x >> 1) * 128;
    int colBase = (blockIdx.x & 1) * 128;
    int wid = t >> 6, lane = t & 63;
    int lr = lane & 15, kg = (lane >> 4) * 8;

    int task0 = t, task1 = t + 256;
    int ar0 = task0 >> 2, as0 = task0 & 3;   // A row / 16B-seg for task0
    int ar1 = task1 >> 2, as1 = task1 & 3;

    f32x4 acc[2][8];
#pragma unroll
    for (int i = 0; i < 2; ++i)
#pragma unroll
        for (int j = 0; j < 8; ++j) acc[i][j] = (f32x4){0.f, 0.f, 0.f, 0.f};

    // initial stage into buffer 0
    {
        s16x8 v0 = (s16x8)(short)0, v1 = (s16x8)(short)0;
        if (rowBase + ar0 < NN) v0 = *(const s16x8*)&Ab[(rowBase + ar0) * 16 + as0 * 4];
        if (rowBase + ar1 < NN) v1 = *(const s16x8*)&Ab[(rowBase + ar1) * 16 + as1 * 4];
        *(s16x8*)&Als[0][ar0 * 40 + as0 * 8] = v0;
        *(s16x8*)&Als[0][ar1 * 40 + as1 * 8] = v1;
        *(s16x8*)&Bls[0][ar0 * 40 + as0 * 8] =
            *(const s16x8*)&Wt[(size_t)(colBase + ar0) * K + as0 * 8];
        *(s16x8*)&Bls[0][ar1 * 40 + as1 * 8] =
            *(const s16x8*)&Wt[(size_t)(colBase + ar1) * K + as1 * 8];
    }
    __syncthreads();

    int cur = 0;
#pragma unroll
    for (int k0 = 0; k0 < K; k0 += 32) {
        s16x8 pa0, pa1, pb0, pb1;
        bool more = (k0 + 32 < K);
        if (more) {
            const unsigned* ap = Ab + (size_t)((k0 + 32) >> 5) * NP1 * 16;
            pa0 = (s16x8)(short)0;
            pa1 = (s16x8)(short)0;
            if (rowBase + ar0 < NN) pa0 = *(const s16x8*)&ap[(rowBase + ar0) * 16 + as0 * 4];
            if (rowBase + ar1 < NN) pa1 = *(const s16x8*)&ap[(rowBase + ar1) * 16 + as1 * 4];
            pb0 = *(const s16x8*)&Wt[(size_t)(colBase + ar0) * K + k0 + 32 + as0 * 8];
            pb1 = *(const s16x8*)&Wt[(size_t)(colBase + ar1) * K + k0 + 32 + as1 * 8];
        }
        s16x8 a0 = *(const s16x8*)&Als[cur][(wid * 32 + lr) * 40 + kg];
        s16x8 a1 = *(const s16x8*)&Als[cur][(wid * 32 + 16 + lr) * 40 + kg];
#pragma unroll
        for (int nf = 0; nf < 8; ++nf) {
            s16x8 b = *(const s16x8*)&Bls[cur][(nf * 16 + lr) * 40 + kg];
            acc[0][nf] = __builtin_amdgcn_mfma_f32_16x16x32_bf16(a0, b, acc[0][nf], 0, 0, 0);
            acc[1][nf] = __builtin_amdgcn_mfma_f32_16x16x32_bf16(a1, b, acc[1][nf], 0, 0, 0);
        }
        if (more) {
            int nxt = cur ^ 1;
            *(s16x8*)&Als[nxt][ar0 * 40 + as0 * 8] = pa0;
            *(s16x8*)&Als[nxt][ar1 * 40 + as1 * 8] = pa1;
            *(s16x8*)&Bls[nxt][ar0 * 40 + as0 * 8] = pb0;
            *(s16x8*)&Bls[nxt][ar1 * 40 + as1 * 8] = pb1;
            __syncthreads();
            cur = nxt;
        }
    }

    int r4 = (lane >> 4) * 4;
    __syncthreads();   // done reading LDS; reuse below as reduction tables
    float* ps = (float*)&Als[0][0];   // [4][128] floats
    float* pq = (float*)&Bls[0][0];

    if (EPI == EPI_STATS) {
#pragma unroll
        for (int nf = 0; nf < 8; ++nf) {
            int cl = nf * 16 + lr;
            int col = colBase + cl;
            float bcol = bias[col];
            float s_ = 0.f, q_ = 0.f;
#pragma unroll
            for (int mf = 0; mf < 2; ++mf)
#pragma unroll
                for (int r = 0; r < 4; ++r) {
                    int row = rowBase + wid * 32 + mf * 16 + r4 + r;
                    bool ok = row < NN;
                    float vv = ok ? fmaxf(acc[mf][nf][r] + bcol, 0.f) : 0.f;
                    s_ += vv;
                    q_ = fmaf(vv, vv, q_);
                    if (ok)
                        Cout[((size_t)(col >> 5) * NP1 + row) * 32 + (col & 31)]
                            = f2bf(vv * dis[row]);
                }
            s_ += __shfl_xor(s_, 16); s_ += __shfl_xor(s_, 32);
            q_ += __shfl_xor(q_, 16); q_ += __shfl_xor(q_, 32);
            if (lane < 16) { ps[wid * 128 + cl] = s_; pq[wid * 128 + cl] = q_; }
        }
        __syncthreads();
        if (t < 128) {
            float ssum = ps[t] + ps[128 + t] + ps[256 + t] + ps[384 + t];
            float qsum = pq[t] + pq[128 + t] + pq[256 + t] + pq[384 + t];
            float* sb = stats8 + (size_t)((blockIdx.x >> 1) & 7) * 2 * HD;
            atomicAdd(&sb[colBase + t], ssum);
            atomicAdd(&sb[HD + colBase + t], qsum);
        }
    } else {
        // EPI_POOL
        int nvalid = NN - rowBase;
        int lastRow = rowBase + (nvalid < 128 ? nvalid : 128) - 1;
        int gA = batch[rowBase];
        int gB = batch[lastRow];
        if (gB - gA <= 1) {
            int split = (gB > gA) ? gstart[gB] : (rowBase + 128);
#pragma unroll
            for (int nf = 0; nf < 8; ++nf) {
                int cl = nf * 16 + lr;
                float bcol = bias[colBase + cl];
                float s_ = 0.f;
#pragma unroll
                for (int mf = 0; mf < 2; ++mf)
#pragma unroll
                    for (int r = 0; r < 4; ++r) {
                        int row = rowBase + wid * 32 + mf * 16 + r4 + r;
                        float vv = fmaxf(acc[mf][nf][r] + bcol, 0.f);
                        s_ += (row < NN && row < split) ? vv : 0.f;
                    }
                s_ += __shfl_xor(s_, 16); s_ += __shfl_xor(s_, 32);
                if (lane < 16) ps[wid * 128 + cl] = s_;
            }
            __syncthreads();
            if (t < 128) {
                float tot = ps[t] + ps[128 + t] + ps[256 + t] + ps[384 + t];
                atomicAdd(&pooled[gA * HD + colBase + t], tot);
            }
            if (gB > gA) {
                __syncthreads();
#pragma unroll
                for (int nf = 0; nf < 8; ++nf) {
                    int cl = nf * 16 + lr;
                    float bcol = bias[colBase + cl];
                    float s_ = 0.f;
#pragma unroll
                    for (int mf = 0; mf < 2; ++mf)
#pragma unroll
                        for (int r = 0; r < 4; ++r) {
                            int row = rowBase + wid * 32 + mf * 16 + r4 + r;
                            float vv = fmaxf(acc[mf][nf][r] + bcol, 0.f);
                            s_ += (row < NN && row >= split) ? vv : 0.f;
                        }
                    s_ += __shfl_xor(s_, 16); s_ += __shfl_xor(s_, 32);
                    if (lane < 16) ps[wid * 128 + cl] = s_;
                }
                __syncthreads();
                if (t < 128) {
                    float tot = ps[t] + ps[128 + t] + ps[256 + t] + ps[384 + t];
                    atomicAdd(&pooled[gB * HD + colBase + t], tot);
                }
            }
        } else {
#pragma unroll
            for (int mf = 0; mf < 2; ++mf)
#pragma unroll
                for (int r = 0; r < 4; ++r) {
                    int row = rowBase + wid * 32 + mf * 16 + r4 + r;
                    if (row < NN) {
                        int g = batch[row];
#pragma unroll
                        for (int nf = 0; nf < 8; ++nf) {
                            int col = colBase + nf * 16 + lr;
                            float vv = fmaxf(acc[mf][nf][r] + bias[col], 0.f);
                            atomicAdd(&pooled[g * HD + col], vv);
                        }
                    }
                }
        }
    }
}

// ---------------- chunked GCN aggregate (+optional BN affine fold) ----------------

template<int NCHUNK, bool AFFINE>
__global__ __launch_bounds__(256) void k_aggc(const unsigned* __restrict__ tin,
                                              const int* __restrict__ rowptr,
                                              const unsigned short* __restrict__ csru,
                                              const float* __restrict__ dis,
                                              const float* __restrict__ aff_a,
                                              const float* __restrict__ aff_c,
                                              const float* __restrict__ dsum,
                                              unsigned* __restrict__ outp) {
    int c = blockIdx.x & (NCHUNK - 1);
    int g = blockIdx.x / NCHUNK;
    int local = threadIdx.x >> 4;
    int jj = threadIdx.x & 15;
    int n = g * 16 + local;
    if (n >= NN) return;
    const unsigned* tc = tin + (size_t)c * NP1 * 16;
    unsigned u0 = tc[n * 16 + jj];
    float acc0 = bflo(u0), acc1 = bfhi(u0);
    int e0 = rowptr[n], e1 = rowptr[n + 1];
    int e = e0;
    for (; e + 8 <= e1; e += 8) {
        const unsigned* p32 = (const unsigned*)(csru + e);
        unsigned i01 = p32[0], i23 = p32[1], i45 = p32[2], i67 = p32[3];
        unsigned v0 = tc[(i01 & 0xffffu) * 16 + jj];
        unsigned v1 = tc[(i01 >> 16) * 16 + jj];
        unsigned v2 = tc[(i23 & 0xffffu) * 16 + jj];
        unsigned v3 = tc[(i23 >> 16) * 16 + jj];
        unsigned v4 = tc[(i45 & 0xffffu) * 16 + jj];
        unsigned v5 = tc[(i45 >> 16) * 16 + jj];
        unsigned v6 = tc[(i67 & 0xffffu) * 16 + jj];
        unsigned v7 = tc[(i67 >> 16) * 16 + jj];
        acc0 += bflo(v0); acc1 += bfhi(v0);
        acc0 += bflo(v1); acc1 += bfhi(v1);
        acc0 += bflo(v2); acc1 += bfhi(v2);
        acc0 += bflo(v3); acc1 += bfhi(v3);
        acc0 += bflo(v4); acc1 += bfhi(v4);
        acc0 += bflo(v5); acc1 += bfhi(v5);
        acc0 += bflo(v6); acc1 += bfhi(v6);
        acc0 += bflo(v7); acc1 += bfhi(v7);
    }
    for (; e < e1; e += 2) {
        unsigned i01 = *(const unsigned*)(csru + e);
        unsigned v0 = tc[(i01 & 0xffffu) * 16 + jj];
        unsigned v1 = tc[(i01 >> 16) * 16 + jj];
        acc0 += bflo(v0) + bflo(v1);
        acc1 += bfhi(v0) + bfhi(v1);
    }
    float dn = dis[n];
    if (AFFINE) {
        float wn = dsum[n];
        int col2 = c * 16 + jj;
        float2 a2 = *(const float2*)&aff_a[2 * col2];
        float2 c2 = *(const float2*)&aff_c[2 * col2];
        acc0 = dn * fmaf(a2.x, acc0, c2.x * wn);
        acc1 = dn * fmaf(a2.y, acc1, c2.y * wn);
    } else {
        acc0 *= dn;
        acc1 *= dn;
    }
    outp[((size_t)c * NP1 + n) * 16 + jj] = ((unsigned)f2bf(acc1) << 16) | f2bf(acc0);
}

// ---------------- BN affine from 8-slot stats ----------------

__global__ void k_affine(const float* __restrict__ stats8, const float* __restrict__ g,
                         const float* __restrict__ be, float* __restrict__ a,
                         float* __restrict__ c) {
    int j = threadIdx.x;
    float s = 0.f, q = 0.f;
    for (int b = 0; b < 8; ++b) {
        s += stats8[(size_t)b * 2 * HD + j];
        q += stats8[(size_t)b * 2 * HD + HD + j];
    }
    float mu = s * (1.0f / NN);
    float var = q * (1.0f / NN) - mu * mu;
    float rs = rsqrtf(var + BN_EPS);
    float aj = g[j] * rs;
    a[j] = aj;
    c[j] = be[j] - mu * aj;
}

// ---------------- pool bounds / finalize ----------------

__global__ void k_bounds(const int* __restrict__ batch, int* __restrict__ gstart) {
    int g = threadIdx.x;
    if (g <= GN) {
        int lo = 0, hi = NN;
        while (lo < hi) {
            int mid = (lo + hi) >> 1;
            if (batch[mid] < g) lo = mid + 1; else hi = mid;
        }
        gstart[g] = lo;
    }
}

__global__ void k_poolfin(float* __restrict__ pooled, const int* __restrict__ gstart) {
    int idx = blockIdx.x * blockDim.x + threadIdx.x;
    if (idx < GN * HD) {
        int g = idx >> 8;
        float c = (float)max(gstart[g + 1] - gstart[g], 1);
        pooled[idx] /= c;
    }
}

// ---------------- MLP head ----------------

__global__ __launch_bounds__(256) void k_head1(const float* __restrict__ pooled,
                                               const float* __restrict__ actions,
                                               const float* __restrict__ fW1,
                                               const float* __restrict__ fb1,
                                               float* __restrict__ z1) {
    int g = blockIdx.x, j = threadIdx.x;
    float acc = fb1[j];
    for (int k = 0; k < HD; ++k)
        acc = fmaf(pooled[g * HD + k], fW1[k * HD + j], acc);
    for (int k = 0; k < AD; ++k)
        acc = fmaf(actions[k], fW1[(HD + k) * HD + j], acc);
    z1[g * HD + j] = fmaxf(acc, 0.f);
}

__global__ __launch_bounds__(256) void k_headbn(float* __restrict__ z1,
                                                const float* __restrict__ g3,
                                                const float* __restrict__ be3) {
    int j = threadIdx.x;
    float s = 0.f, q = 0.f;
    for (int g = 0; g < GN; ++g) {
        float v = z1[g * HD + j];
        s += v;
        q = fmaf(v, v, q);
    }
    float mu = s * (1.0f / GN);
    float var = q * (1.0f / GN) - mu * mu;
    float rs = rsqrtf(var + BN_EPS);
    float ga = g3[j], be = be3[j];
    for (int g = 0; g < GN; ++g)
        z1[g * HD + j] = fmaf((z1[g * HD + j] - mu) * rs, ga, be);
}

__global__ __launch_bounds__(128) void k_head2(const float* __restrict__ z1,
                                               const float* __restrict__ fW2,
                                               const float* __restrict__ fb2,
                                               float* __restrict__ z2) {
    int g = blockIdx.x, j = threadIdx.x;
    float acc = fb2[j];
    for (int k = 0; k < HD; ++k)
        acc = fmaf(z1[g * HD + k], fW2[k * (HD / 2) + j], acc);
    z2[g * (HD / 2) + j] = fmaxf(acc, 0.f);
}

__global__ __launch_bounds__(64) void k_head3(const float* __restrict__ z2,
                                              const float* __restrict__ fW3,
                                              const float* __restrict__ fb3,
                                              float* __restrict__ out) {
    int g = threadIdx.x;
    if (g < GN) {
        float acc = fb3[0];
        for (int k = 0; k < HD / 2; ++k)
            acc = fmaf(z2[g * (HD / 2) + k], fW3[k], acc);
        out[g] = acc;
    }
}

// ---------------- launch ----------------

static inline size_t align256(size_t x) { return (x + 255) & ~(size_t)255; }

extern "C" void kernel_launch(void* const* d_in, const int* in_sizes, int n_in,
                              void* d_out, int out_size, void* d_ws, size_t ws_size,
                              hipStream_t stream) {
    const float* x       = (const float*)d_in[0];
    const int*   ei      = (const int*)d_in[1];
    const int*   batch   = (const int*)d_in[2];
    const float* actions = (const float*)d_in[3];
    const float* W1 = (const float*)d_in[4];
    const float* b1 = (const float*)d_in[5];
    const float* W2 = (const float*)d_in[6];
    const float* b2 = (const float*)d_in[7];
    const float* W3 = (const float*)d_in[8];
    const float* b3 = (const float*)d_in[9];
    const float* g1  = (const float*)d_in[10];
    const float* be1 = (const float*)d_in[11];
    const float* g2  = (const float*)d_in[12];
    const float* be2 = (const float*)d_in[13];
    const float* g3  = (const float*)d_in[14];
    const float* be3 = (const float*)d_in[15];
    const float* fW1 = (const float*)d_in[16];
    const float* fb1 = (const float*)d_in[17];
    const float* fW2 = (const float*)d_in[18];
    const float* fb2 = (const float*)d_in[19];
    const float* fW3 = (const float*)d_in[20];
    const float* fb3 = (const float*)d_in[21];
    float* out = (float*)d_out;

    const int* esrc = ei;
    const int* edst = ei + NE;

    // workspace carve
    char* p = (char*)d_ws;
    size_t off = 0;
    auto carve = [&](size_t bytes) { void* r = p + off; off = align256(off + bytes); return r; };
    unsigned* xb   = (unsigned*)carve((size_t)4 * NP1 * 16 * 4);
    unsigned* xa   = (unsigned*)carve((size_t)4 * NP1 * 16 * 4);
    unsigned* tbuf = (unsigned*)carve((size_t)8 * NP1 * 16 * 4);
    unsigned* ah   = (unsigned*)carve((size_t)8 * NP1 * 16 * 4);
    float* dis     = (float*)carve((size_t)NP1 * 4);
    int*   counts  = (int*)carve((size_t)NN * 4);
    int*   rowptr  = (int*)carve((size_t)(NN + 1) * 4);
    int*   fill    = (int*)carve((size_t)NN * 4);
    unsigned short* csru = (unsigned short*)carve((size_t)(NE + NN) * 2);
    float* dsum    = (float*)carve((size_t)NN * 4);
    int*   bsum    = (int*)carve(64 * 4);
    float* pooled  = (float*)carve((size_t)GN * HD * 4);
    int*   gstart  = (int*)carve((size_t)(GN + 1) * 4);
    float* stats8  = (float*)carve((size_t)8 * 2 * HD * 4);
    float* affa    = (float*)carve(HD * 4);
    float* affc    = (float*)carve(HD * 4);
    float* z1      = (float*)carve((size_t)GN * HD * 4);
    float* z2      = (float*)carve((size_t)GN * (HD / 2) * 4);
    unsigned short* W1t = (unsigned short*)carve((size_t)FD * HD * 2);
    unsigned short* W2t = (unsigned short*)carve((size_t)HD * HD * 2);
    unsigned short* W3t = (unsigned short*)carve((size_t)HD * HD * 2);
    (void)ws_size;

    const int TB = 256;
    const int ebk = (NE + TB - 1) / TB;
    const int nbk = (NN + TB - 1) / TB;
    const int scanblk = (NN + 1023) / 1024;
    const int mmg2 = ((NN + 127) / 128) * 2;   // 782
    const int ngrp = NN / 16;                  // 3125

    // weight casts
    k_castW<<<(FD * HD + 255) / 256, 256, 0, stream>>>(W1, W1t, FD);
    k_castW<<<(HD * HD + 255) / 256, 256, 0, stream>>>(W2, W2t, HD);
    k_castW<<<(HD * HD + 255) / 256, 256, 0, stream>>>(W3, W3t, HD);

    // degree + CSR (ushort, even-padded rows)
    hipMemsetAsync(counts, 0, (size_t)NN * 4, stream);
    k_deg<<<ebk, TB, 0, stream>>>(edst, counts);
    k_dis<<<nbk, TB, 0, stream>>>(counts, dis);
    k_scan1<<<scanblk, 1024, 0, stream>>>(counts, rowptr, bsum);
    k_scan2<<<1, 64, 0, stream>>>(bsum, rowptr, scanblk);
    k_scan3<<<nbk, TB, 0, stream>>>(rowptr, bsum);
    hipMemsetAsync(fill, 0, (size_t)NN * 4, stream);
    k_csr<<<ebk, TB, 0, stream>>>(esrc, edst, rowptr, fill, csru);
    k_pad<<<nbk, TB, 0, stream>>>(counts, rowptr, csru);
    k_dsum<<<nbk, TB, 0, stream>>>(rowptr, csru, dis, dsum);
    k_bounds<<<1, 64, 0, stream>>>(batch, gstart);

    // input cast + zero pad rows
    k_castx<<<(NN * (FD / 2) + 255) / 256, 256, 0, stream>>>(x, dis, xb);
    k_zrow<<<1, 192, 0, stream>>>(xb, tbuf);

    // layer 1: agg(x') -> GEMM(+b1,relu,*dis, fused stats) -> t1'; affine
    hipMemsetAsync(stats8, 0, (size_t)8 * 2 * HD * 4, stream);
    k_aggc<4, false><<<4 * ngrp, TB, 0, stream>>>(xb, rowptr, csru, dis,
                                                  nullptr, nullptr, nullptr, xa);
    k_mm2<FD, EPI_STATS><<<mmg2, TB, 0, stream>>>(xa, W1t, b1, dis, (unsigned short*)tbuf,
                                                  stats8, nullptr, nullptr, nullptr);
    k_affine<<<1, HD, 0, stream>>>(stats8, g1, be1, affa, affc);

    // layer 2: aggBN(t1') -> GEMM(+b2,relu,*dis, fused stats) -> t2'; affine
    hipMemsetAsync(stats8, 0, (size_t)8 * 2 * HD * 4, stream);
    k_aggc<8, true><<<8 * ngrp, TB, 0, stream>>>(tbuf, rowptr, csru, dis,
                                                 affa, affc, dsum, ah);
    k_mm2<HD, EPI_STATS><<<mmg2, TB, 0, stream>>>(ah, W2t, b2, dis, (unsigned short*)tbuf,
                                                  stats8, nullptr, nullptr, nullptr);
    k_affine<<<1, HD, 0, stream>>>(stats8, g2, be2, affa, affc);

    // layer 3: aggBN(t2') -> GEMM(+b3,relu) with boundary-aware fused mean-pool
    hipMemsetAsync(pooled, 0, (size_t)GN * HD * 4, stream);
    k_aggc<8, true><<<8 * ngrp, TB, 0, stream>>>(tbuf, rowptr, csru, dis,
                                                 affa, affc, dsum, ah);
    k_mm2<HD, EPI_POOL><<<mmg2, TB, 0, stream>>>(ah, W3t, b3, dis, nullptr,
                                                 nullptr, batch, gstart, pooled);

    // pool finalize
    k_poolfin<<<(GN * HD + TB - 1) / TB, TB, 0, stream>>>(pooled, gstart);

    // head
    k_head1<<<GN, TB, 0, stream>>>(pooled, actions, fW1, fb1, z1);
    k_headbn<<<1, TB, 0, stream>>>(z1, g3, be3);
    k_head2<<<GN, 128, 0, stream>>>(z1, fW2, fb2, z2);
    k_head3<<<1, 64, 0, stream>>>(z2, fW3, fb3, out);
}

// Round 12
// 395.992 us; speedup vs baseline: 1.0398x; 1.0398x over previous
//
#include <hip/hip_runtime.h>

#define NN 50000      // nodes
#define NP1 (NN + 1)  // +1 virtual zero row for even-padding
#define NE 800000     // edges
#define FD 128        // input feature dim
#define HD 256        // hidden dim
#define AD 32         // action dim
#define GN 50         // graphs
#define BN_EPS 1e-5f

#define EPI_STATS 0
#define EPI_POOL  1

typedef float f32x4 __attribute__((ext_vector_type(4)));
typedef short s16x8 __attribute__((ext_vector_type(8)));

__device__ inline unsigned short f2bf(float f) {
    unsigned u = __float_as_uint(f);
    u += 0x7FFF + ((u >> 16) & 1);   // round-to-nearest-even
    return (unsigned short)(u >> 16);
}
__device__ inline float bflo(unsigned u) { return __uint_as_float(u << 16); }
__device__ inline float bfhi(unsigned u) { return __uint_as_float(u & 0xffff0000u); }

// ---------------- degree / CSR build ----------------

__global__ void k_deg(const int* __restrict__ dst, int* __restrict__ counts) {
    int e = blockIdx.x * blockDim.x + threadIdx.x;
    if (e < NE) atomicAdd(&counts[dst[e]], 1);
}

__global__ void k_dis(const int* __restrict__ counts, float* __restrict__ dis) {
    int i = blockIdx.x * blockDim.x + threadIdx.x;
    if (i < NN) dis[i] = rsqrtf(1.0f + (float)counts[i]);
    if (i == 0) dis[NN] = 0.0f;
}

__global__ void k_scan1(const int* __restrict__ counts, int* __restrict__ rowptr,
                        int* __restrict__ bsum) {
    __shared__ int s[1024];
    int t = threadIdx.x;
    int i = blockIdx.x * 1024 + t;
    int v = (i < NN) ? ((counts[i] + 1) & ~1) : 0;
    s[t] = v;
    __syncthreads();
    for (int off = 1; off < 1024; off <<= 1) {
        int u = (t >= off) ? s[t - off] : 0;
        __syncthreads();
        s[t] += u;
        __syncthreads();
    }
    if (i < NN) rowptr[i + 1] = s[t];
    if (t == 1023) bsum[blockIdx.x] = s[1023];
}

__global__ void k_scan2(int* __restrict__ bsum, int* __restrict__ rowptr, int nblk) {
    if (threadIdx.x == 0 && blockIdx.x == 0) {
        int run = 0;
        for (int b = 0; b < nblk; ++b) { int t = bsum[b]; bsum[b] = run; run += t; }
        rowptr[0] = 0;
    }
}

__global__ void k_scan3(int* __restrict__ rowptr, const int* __restrict__ bsum) {
    int i = blockIdx.x * blockDim.x + threadIdx.x;
    if (i < NN) rowptr[i + 1] += bsum[i >> 10];
}

__global__ void k_csr(const int* __restrict__ src, const int* __restrict__ dst,
                      const int* __restrict__ rowptr, int* __restrict__ fill,
                      unsigned short* __restrict__ csru) {
    int e = blockIdx.x * blockDim.x + threadIdx.x;
    if (e < NE) {
        int d = dst[e];
        int p = rowptr[d] + atomicAdd(&fill[d], 1);
        csru[p] = (unsigned short)src[e];
    }
}

// pad odd rows (lane 0) + dsum[n] = dis_n + sum_e dis[src_e], 4 lanes/node
__global__ void k_dsum(const int* __restrict__ rowptr, const int* __restrict__ counts,
                       unsigned short* __restrict__ csru,
                       const float* __restrict__ dis, float* __restrict__ dsum) {
    int t = threadIdx.x;
    int n = blockIdx.x * 64 + (t >> 2);
    int r = t & 3;
    if (n >= NN) return;
    int e0 = rowptr[n], c = counts[n];
    if (r == 0 && (c & 1)) csru[e0 + c] = (unsigned short)NN;
    float s = 0.f;
    for (int e = e0 + r; e < e0 + c; e += 4) s += dis[csru[e]];
    s += __shfl_xor(s, 1);
    s += __shfl_xor(s, 2);
    if (r == 0) dsum[n] = s + dis[n];
}

// ---------------- casts ----------------

// all three weight matrices in one launch: Wt[HD][K] bf16 from W[K][HD] fp32
__global__ void k_castW3(const float* __restrict__ W1, const float* __restrict__ W2,
                         const float* __restrict__ W3,
                         unsigned short* __restrict__ W1t,
                         unsigned short* __restrict__ W2t,
                         unsigned short* __restrict__ W3t) {
    int idx = blockIdx.x * 256 + threadIdx.x;
    const int N1 = FD * HD, N2 = HD * HD;
    if (idx < N1) {
        int c = idx / FD, k = idx - c * FD;
        W1t[idx] = f2bf(W1[(size_t)k * HD + c]);
    } else if (idx < N1 + N2) {
        int j = idx - N1;
        int c = j / HD, k = j - c * HD;
        W2t[j] = f2bf(W2[(size_t)k * HD + c]);
    } else if (idx < N1 + 2 * N2) {
        int j = idx - N1 - N2;
        int c = j / HD, k = j - c * HD;
        W3t[j] = f2bf(W3[(size_t)k * HD + c]);
    }
}

// x cast (chunked, dis-scaled) + zero the virtual pad rows of xb and tbuf
__global__ void k_castx(const float* __restrict__ x, const float* __restrict__ dis,
                        unsigned* __restrict__ xb, unsigned* __restrict__ tbuf) {
    int idx = blockIdx.x * 256 + threadIdx.x;
    const int total = NN * (FD / 2);
    if (idx < total) {
        int n = idx >> 6, jj = idx & 63;
        int chunk = jj >> 4, w = jj & 15;
        float sc = dis[n];
        float2 v = *(const float2*)&x[(size_t)n * FD + jj * 2];
        xb[((size_t)chunk * NP1 + n) * 16 + w] =
            ((unsigned)f2bf(v.y * sc) << 16) | f2bf(v.x * sc);
    } else {
        int q = idx - total;
        if (q < 64) xb[((size_t)(q >> 4) * NP1 + NN) * 16 + (q & 15)] = 0;
        else if (q < 192) {
            int r = q - 64;
            tbuf[((size_t)(r >> 4) * NP1 + NN) * 16 + (r & 15)] = 0;
        }
    }
}

// ---------------- MFMA bf16 GEMM, 128x128 tile, double-buffered staging ----------------

template<int K, int EPI>
__global__ __launch_bounds__(256) void k_mm2(const unsigned* __restrict__ Ab,
                                             const unsigned short* __restrict__ Wt,
                                             const float* __restrict__ bias,
                                             const float* __restrict__ dis,
                                             unsigned short* __restrict__ Cout,
                                             float* __restrict__ stats8,
                                             const int* __restrict__ batch,
                                             const int* __restrict__ gstart,
                                             float* __restrict__ pooled) {
    __shared__ __align__(16) short Als[2][128 * 40];
    __shared__ __align__(16) short Bls[2][128 * 40];
    int t = threadIdx.x;
    int rowBase = (blockIdx.x >> 1) * 128;
    int colBase = (blockIdx.x & 1) * 128;
    int wid = t >> 6, lane = t & 63;
    int lr = lane & 15, kg = (lane >> 4) * 8;

    int task0 = t, task1 = t + 256;
    int ar0 = task0 >> 2, as0 = task0 & 3;
    int ar1 = task1 >> 2, as1 = task1 & 3;

    f32x4 acc[2][8];
#pragma unroll
    for (int i = 0; i < 2; ++i)
#pragma unroll
        for (int j = 0; j < 8; ++j) acc[i][j] = (f32x4){0.f, 0.f, 0.f, 0.f};

    {
        s16x8 v0 = (s16x8)(short)0, v1 = (s16x8)(short)0;
        if (rowBase + ar0 < NN) v0 = *(const s16x8*)&Ab[(rowBase + ar0) * 16 + as0 * 4];
        if (rowBase + ar1 < NN) v1 = *(const s16x8*)&Ab[(rowBase + ar1) * 16 + as1 * 4];
        *(s16x8*)&Als[0][ar0 * 40 + as0 * 8] = v0;
        *(s16x8*)&Als[0][ar1 * 40 + as1 * 8] = v1;
        *(s16x8*)&Bls[0][ar0 * 40 + as0 * 8] =
            *(const s16x8*)&Wt[(size_t)(colBase + ar0) * K + as0 * 8];
        *(s16x8*)&Bls[0][ar1 * 40 + as1 * 8] =
            *(const s16x8*)&Wt[(size_t)(colBase + ar1) * K + as1 * 8];
    }
    __syncthreads();

    int cur = 0;
#pragma unroll
    for (int k0 = 0; k0 < K; k0 += 32) {
        s16x8 pa0, pa1, pb0, pb1;
        bool more = (k0 + 32 < K);
        if (more) {
            const unsigned* ap = Ab + (size_t)((k0 + 32) >> 5) * NP1 * 16;
            pa0 = (s16x8)(short)0;
            pa1 = (s16x8)(short)0;
            if (rowBase + ar0 < NN) pa0 = *(const s16x8*)&ap[(rowBase + ar0) * 16 + as0 * 4];
            if (rowBase + ar1 < NN) pa1 = *(const s16x8*)&ap[(rowBase + ar1) * 16 + as1 * 4];
            pb0 = *(const s16x8*)&Wt[(size_t)(colBase + ar0) * K + k0 + 32 + as0 * 8];
            pb1 = *(const s16x8*)&Wt[(size_t)(colBase + ar1) * K + k0 + 32 + as1 * 8];
        }
        s16x8 a0 = *(const s16x8*)&Als[cur][(wid * 32 + lr) * 40 + kg];
        s16x8 a1 = *(const s16x8*)&Als[cur][(wid * 32 + 16 + lr) * 40 + kg];
#pragma unroll
        for (int nf = 0; nf < 8; ++nf) {
            s16x8 b = *(const s16x8*)&Bls[cur][(nf * 16 + lr) * 40 + kg];
            acc[0][nf] = __builtin_amdgcn_mfma_f32_16x16x32_bf16(a0, b, acc[0][nf], 0, 0, 0);
            acc[1][nf] = __builtin_amdgcn_mfma_f32_16x16x32_bf16(a1, b, acc[1][nf], 0, 0, 0);
        }
        if (more) {
            int nxt = cur ^ 1;
            *(s16x8*)&Als[nxt][ar0 * 40 + as0 * 8] = pa0;
            *(s16x8*)&Als[nxt][ar1 * 40 + as1 * 8] = pa1;
            *(s16x8*)&Bls[nxt][ar0 * 40 + as0 * 8] = pb0;
            *(s16x8*)&Bls[nxt][ar1 * 40 + as1 * 8] = pb1;
            __syncthreads();
            cur = nxt;
        }
    }

    int r4 = (lane >> 4) * 4;
    __syncthreads();
    float* ps = (float*)&Als[0][0];
    float* pq = (float*)&Bls[0][0];

    if (EPI == EPI_STATS) {
#pragma unroll
        for (int nf = 0; nf < 8; ++nf) {
            int cl = nf * 16 + lr;
            int col = colBase + cl;
            float bcol = bias[col];
            float s_ = 0.f, q_ = 0.f;
#pragma unroll
            for (int mf = 0; mf < 2; ++mf)
#pragma unroll
                for (int r = 0; r < 4; ++r) {
                    int row = rowBase + wid * 32 + mf * 16 + r4 + r;
                    bool ok = row < NN;
                    float vv = ok ? fmaxf(acc[mf][nf][r] + bcol, 0.f) : 0.f;
                    s_ += vv;
                    q_ = fmaf(vv, vv, q_);
                    if (ok)
                        Cout[((size_t)(col >> 5) * NP1 + row) * 32 + (col & 31)]
                            = f2bf(vv * dis[row]);
                }
            s_ += __shfl_xor(s_, 16); s_ += __shfl_xor(s_, 32);
            q_ += __shfl_xor(q_, 16); q_ += __shfl_xor(q_, 32);
            if (lane < 16) { ps[wid * 128 + cl] = s_; pq[wid * 128 + cl] = q_; }
        }
        __syncthreads();
        if (t < 128) {
            float ssum = ps[t] + ps[128 + t] + ps[256 + t] + ps[384 + t];
            float qsum = pq[t] + pq[128 + t] + pq[256 + t] + pq[384 + t];
            float* sb = stats8 + (size_t)((blockIdx.x >> 1) & 7) * 2 * HD;
            atomicAdd(&sb[colBase + t], ssum);
            atomicAdd(&sb[HD + colBase + t], qsum);
        }
    } else {
        int nvalid = NN - rowBase;
        int lastRow = rowBase + (nvalid < 128 ? nvalid : 128) - 1;
        int gA = batch[rowBase];
        int gB = batch[lastRow];
        if (gB - gA <= 1) {
            int split = (gB > gA) ? gstart[gB] : (rowBase + 128);
#pragma unroll
            for (int nf = 0; nf < 8; ++nf) {
                int cl = nf * 16 + lr;
                float bcol = bias[colBase + cl];
                float s_ = 0.f;
#pragma unroll
                for (int mf = 0; mf < 2; ++mf)
#pragma unroll
                    for (int r = 0; r < 4; ++r) {
                        int row = rowBase + wid * 32 + mf * 16 + r4 + r;
                        float vv = fmaxf(acc[mf][nf][r] + bcol, 0.f);
                        s_ += (row < NN && row < split) ? vv : 0.f;
                    }
                s_ += __shfl_xor(s_, 16); s_ += __shfl_xor(s_, 32);
                if (lane < 16) ps[wid * 128 + cl] = s_;
            }
            __syncthreads();
            if (t < 128) {
                float tot = ps[t] + ps[128 + t] + ps[256 + t] + ps[384 + t];
                atomicAdd(&pooled[gA * HD + colBase + t], tot);
            }
            if (gB > gA) {
                __syncthreads();
#pragma unroll
                for (int nf = 0; nf < 8; ++nf) {
                    int cl = nf * 16 + lr;
                    float bcol = bias[colBase + cl];
                    float s_ = 0.f;
#pragma unroll
                    for (int mf = 0; mf < 2; ++mf)
#pragma unroll
                        for (int r = 0; r < 4; ++r) {
                            int row = rowBase + wid * 32 + mf * 16 + r4 + r;
                            float vv = fmaxf(acc[mf][nf][r] + bcol, 0.f);
                            s_ += (row < NN && row >= split) ? vv : 0.f;
                        }
                    s_ += __shfl_xor(s_, 16); s_ += __shfl_xor(s_, 32);
                    if (lane < 16) ps[wid * 128 + cl] = s_;
                }
                __syncthreads();
                if (t < 128) {
                    float tot = ps[t] + ps[128 + t] + ps[256 + t] + ps[384 + t];
                    atomicAdd(&pooled[gB * HD + colBase + t], tot);
                }
            }
        } else {
#pragma unroll
            for (int mf = 0; mf < 2; ++mf)
#pragma unroll
                for (int r = 0; r < 4; ++r) {
                    int row = rowBase + wid * 32 + mf * 16 + r4 + r;
                    if (row < NN) {
                        int g = batch[row];
#pragma unroll
                        for (int nf = 0; nf < 8; ++nf) {
                            int col = colBase + nf * 16 + lr;
                            float vv = fmaxf(acc[mf][nf][r] + bias[col], 0.f);
                            atomicAdd(&pooled[g * HD + col], vv);
                        }
                    }
                }
        }
    }
}

// ---------------- chunked GCN aggregate (+optional BN affine fold) ----------------
// dual accumulators per half to break the serial fp-add chain

template<int NCHUNK, bool AFFINE>
__global__ __launch_bounds__(256) void k_aggc(const unsigned* __restrict__ tin,
                                              const int* __restrict__ rowptr,
                                              const unsigned short* __restrict__ csru,
                                              const float* __restrict__ dis,
                                              const float* __restrict__ aff_a,
                                              const float* __restrict__ aff_c,
                                              const float* __restrict__ dsum,
                                              unsigned* __restrict__ outp) {
    int c = blockIdx.x & (NCHUNK - 1);
    int g = blockIdx.x / NCHUNK;
    int local = threadIdx.x >> 4;
    int jj = threadIdx.x & 15;
    int n = g * 16 + local;
    if (n >= NN) return;
    const unsigned* tc = tin + (size_t)c * NP1 * 16;
    unsigned u0 = tc[n * 16 + jj];
    float a0a = bflo(u0), a1a = bfhi(u0);
    float a0b = 0.f, a1b = 0.f;
    int e0 = rowptr[n], e1 = rowptr[n + 1];
    int e = e0;
    for (; e + 8 <= e1; e += 8) {
        const unsigned* p32 = (const unsigned*)(csru + e);
        unsigned i01 = p32[0], i23 = p32[1], i45 = p32[2], i67 = p32[3];
        unsigned v0 = tc[(i01 & 0xffffu) * 16 + jj];
        unsigned v1 = tc[(i01 >> 16) * 16 + jj];
        unsigned v2 = tc[(i23 & 0xffffu) * 16 + jj];
        unsigned v3 = tc[(i23 >> 16) * 16 + jj];
        unsigned v4 = tc[(i45 & 0xffffu) * 16 + jj];
        unsigned v5 = tc[(i45 >> 16) * 16 + jj];
        unsigned v6 = tc[(i67 & 0xffffu) * 16 + jj];
        unsigned v7 = tc[(i67 >> 16) * 16 + jj];
        a0a += bflo(v0); a1a += bfhi(v0);
        a0b += bflo(v1); a1b += bfhi(v1);
        a0a += bflo(v2); a1a += bfhi(v2);
        a0b += bflo(v3); a1b += bfhi(v3);
        a0a += bflo(v4); a1a += bfhi(v4);
        a0b += bflo(v5); a1b += bfhi(v5);
        a0a += bflo(v6); a1a += bfhi(v6);
        a0b += bflo(v7); a1b += bfhi(v7);
    }
    for (; e < e1; e += 2) {
        unsigned i01 = *(const unsigned*)(csru + e);
        unsigned v0 = tc[(i01 & 0xffffu) * 16 + jj];
        unsigned v1 = tc[(i01 >> 16) * 16 + jj];
        a0a += bflo(v0); a1a += bfhi(v0);
        a0b += bflo(v1); a1b += bfhi(v1);
    }
    float acc0 = a0a + a0b;
    float acc1 = a1a + a1b;
    float dn = dis[n];
    if (AFFINE) {
        float wn = dsum[n];
        int col2 = c * 16 + jj;
        float2 a2 = *(const float2*)&aff_a[2 * col2];
        float2 c2 = *(const float2*)&aff_c[2 * col2];
        acc0 = dn * fmaf(a2.x, acc0, c2.x * wn);
        acc1 = dn * fmaf(a2.y, acc1, c2.y * wn);
    } else {
        acc0 *= dn;
        acc1 *= dn;
    }
    outp[((size_t)c * NP1 + n) * 16 + jj] = ((unsigned)f2bf(acc1) << 16) | f2bf(acc0);
}

// ---------------- BN affine from 8-slot stats (+re-zero stats for next use) ----------------

__global__ void k_affine(float* __restrict__ stats8, const float* __restrict__ g,
                         const float* __restrict__ be, float* __restrict__ a,
                         float* __restrict__ c) {
    int j = threadIdx.x;
    float s = 0.f, q = 0.f;
    for (int b = 0; b < 8; ++b) {
        s += stats8[(size_t)b * 2 * HD + j];
        q += stats8[(size_t)b * 2 * HD + HD + j];
        stats8[(size_t)b * 2 * HD + j] = 0.f;
        stats8[(size_t)b * 2 * HD + HD + j] = 0.f;
    }
    float mu = s * (1.0f / NN);
    float var = q * (1.0f / NN) - mu * mu;
    float rs = rsqrtf(var + BN_EPS);
    float aj = g[j] * rs;
    a[j] = aj;
    c[j] = be[j] - mu * aj;
}

// ---------------- pool bounds / finalize ----------------

__global__ void k_bounds(const int* __restrict__ batch, int* __restrict__ gstart) {
    int g = threadIdx.x;
    if (g <= GN) {
        int lo = 0, hi = NN;
        while (lo < hi) {
            int mid = (lo + hi) >> 1;
            if (batch[mid] < g) lo = mid + 1; else hi = mid;
        }
        gstart[g] = lo;
    }
}

__global__ void k_poolfin(float* __restrict__ pooled, const int* __restrict__ gstart) {
    int idx = blockIdx.x * blockDim.x + threadIdx.x;
    if (idx < GN * HD) {
        int g = idx >> 8;
        float c = (float)max(gstart[g + 1] - gstart[g], 1);
        pooled[idx] /= c;
    }
}

// ---------------- MLP head ----------------

__global__ __launch_bounds__(256) void k_head1(const float* __restrict__ pooled,
                                               const float* __restrict__ actions,
                                               const float* __restrict__ fW1,
                                               const float* __restrict__ fb1,
                                               float* __restrict__ z1) {
    int g = blockIdx.x, j = threadIdx.x;
    float acc = fb1[j];
    for (int k = 0; k < HD; ++k)
        acc = fmaf(pooled[g * HD + k], fW1[k * HD + j], acc);
    for (int k = 0; k < AD; ++k)
        acc = fmaf(actions[k], fW1[(HD + k) * HD + j], acc);
    z1[g * HD + j] = fmaxf(acc, 0.f);
}

__global__ __launch_bounds__(256) void k_headbn(float* __restrict__ z1,
                                                const float* __restrict__ g3,
                                                const float* __restrict__ be3) {
    int j = threadIdx.x;
    float s = 0.f, q = 0.f;
    for (int g = 0; g < GN; ++g) {
        float v = z1[g * HD + j];
        s += v;
        q = fmaf(v, v, q);
    }
    float mu = s * (1.0f / GN);
    float var = q * (1.0f / GN) - mu * mu;
    float rs = rsqrtf(var + BN_EPS);
    float ga = g3[j], be = be3[j];
    for (int g = 0; g < GN; ++g)
        z1[g * HD + j] = fmaf((z1[g * HD + j] - mu) * rs, ga, be);
}

__global__ __launch_bounds__(128) void k_head2(const float* __restrict__ z1,
                                               const float* __restrict__ fW2,
                                               const float* __restrict__ fb2,
                                               float* __restrict__ z2) {
    int g = blockIdx.x, j = threadIdx.x;
    float acc = fb2[j];
    for (int k = 0; k < HD; ++k)
        acc = fmaf(z1[g * HD + k], fW2[k * (HD / 2) + j], acc);
    z2[g * (HD / 2) + j] = fmaxf(acc, 0.f);
}

__global__ __launch_bounds__(64) void k_head3(const float* __restrict__ z2,
                                              const float* __restrict__ fW3,
                                              const float* __restrict__ fb3,
                                              float* __restrict__ out) {
    int g = threadIdx.x;
    if (g < GN) {
        float acc = fb3[0];
        for (int k = 0; k < HD / 2; ++k)
            acc = fmaf(z2[g * (HD / 2) + k], fW3[k], acc);
        out[g] = acc;
    }
}

// ---------------- launch ----------------

static inline size_t align256(size_t x) { return (x + 255) & ~(size_t)255; }

extern "C" void kernel_launch(void* const* d_in, const int* in_sizes, int n_in,
                              void* d_out, int out_size, void* d_ws, size_t ws_size,
                              hipStream_t stream) {
    const float* x       = (const float*)d_in[0];
    const int*   ei      = (const int*)d_in[1];
    const int*   batch   = (const int*)d_in[2];
    const float* actions = (const float*)d_in[3];
    const float* W1 = (const float*)d_in[4];
    const float* b1 = (const float*)d_in[5];
    const float* W2 = (const float*)d_in[6];
    const float* b2 = (const float*)d_in[7];
    const float* W3 = (const float*)d_in[8];
    const float* b3 = (const float*)d_in[9];
    const float* g1  = (const float*)d_in[10];
    const float* be1 = (const float*)d_in[11];
    const float* g2  = (const float*)d_in[12];
    const float* be2 = (const float*)d_in[13];
    const float* g3  = (const float*)d_in[14];
    const float* be3 = (const float*)d_in[15];
    const float* fW1 = (const float*)d_in[16];
    const float* fb1 = (const float*)d_in[17];
    const float* fW2 = (const float*)d_in[18];
    const float* fb2 = (const float*)d_in[19];
    const float* fW3 = (const float*)d_in[20];
    const float* fb3 = (const float*)d_in[21];
    float* out = (float*)d_out;

    const int* esrc = ei;
    const int* edst = ei + NE;

    // workspace carve
    char* p = (char*)d_ws;
    size_t off = 0;
    auto carve = [&](size_t bytes) { void* r = p + off; off = align256(off + bytes); return r; };
    unsigned* xb   = (unsigned*)carve((size_t)4 * NP1 * 16 * 4);
    unsigned* xa   = (unsigned*)carve((size_t)4 * NP1 * 16 * 4);
    unsigned* tbuf = (unsigned*)carve((size_t)8 * NP1 * 16 * 4);
    unsigned* ah   = (unsigned*)carve((size_t)8 * NP1 * 16 * 4);
    float* dis     = (float*)carve((size_t)NP1 * 4);
    int*   counts  = (int*)carve((size_t)NN * 4);
    int*   fill    = (int*)carve((size_t)NN * 4);
    int*   rowptr  = (int*)carve((size_t)(NN + 1) * 4);
    unsigned short* csru = (unsigned short*)carve((size_t)(NE + NN) * 2);
    float* dsum    = (float*)carve((size_t)NN * 4);
    int*   bsum    = (int*)carve(64 * 4);
    float* pooled  = (float*)carve((size_t)GN * HD * 4);
    int*   gstart  = (int*)carve((size_t)(GN + 1) * 4);
    float* stats8  = (float*)carve((size_t)8 * 2 * HD * 4);
    float* affa    = (float*)carve(HD * 4);
    float* affc    = (float*)carve(HD * 4);
    float* z1      = (float*)carve((size_t)GN * HD * 4);
    float* z2      = (float*)carve((size_t)GN * (HD / 2) * 4);
    unsigned short* W1t = (unsigned short*)carve((size_t)FD * HD * 2);
    unsigned short* W2t = (unsigned short*)carve((size_t)HD * HD * 2);
    unsigned short* W3t = (unsigned short*)carve((size_t)HD * HD * 2);
    (void)ws_size;

    const int TB = 256;
    const int ebk = (NE + TB - 1) / TB;
    const int nbk = (NN + TB - 1) / TB;
    const int nbk64 = (NN + 63) / 64;          // 782 (dsum, 4 lanes/node)
    const int scanblk = (NN + 1023) / 1024;
    const int mmg2 = ((NN + 127) / 128) * 2;   // 782
    const int ngrp = NN / 16;                  // 3125
    const int castWblk = (FD * HD + 2 * HD * HD + 255) / 256;
    const int castxblk = (NN * (FD / 2) + 192 + 255) / 256;

    // weight casts (one launch)
    k_castW3<<<castWblk, TB, 0, stream>>>(W1, W2, W3, W1t, W2t, W3t);

    // degree + CSR (ushort, even-padded rows)
    size_t cfbytes = (size_t)((char*)rowptr - (char*)counts);
    hipMemsetAsync(counts, 0, cfbytes, stream);   // counts + fill in one memset
    k_deg<<<ebk, TB, 0, stream>>>(edst, counts);
    k_dis<<<nbk, TB, 0, stream>>>(counts, dis);
    k_scan1<<<scanblk, 1024, 0, stream>>>(counts, rowptr, bsum);
    k_scan2<<<1, 64, 0, stream>>>(bsum, rowptr, scanblk);
    k_scan3<<<nbk, TB, 0, stream>>>(rowptr, bsum);
    k_csr<<<ebk, TB, 0, stream>>>(esrc, edst, rowptr, fill, csru);
    k_dsum<<<nbk64, TB, 0, stream>>>(rowptr, counts, csru, dis, dsum);
    k_bounds<<<1, 64, 0, stream>>>(batch, gstart);

    // input cast + pad-row zeroing
    k_castx<<<castxblk, TB, 0, stream>>>(x, dis, xb, tbuf);

    // layer 1: agg(x') -> GEMM(+b1,relu,*dis, fused stats) -> t1'; affine (re-zeroes stats8)
    hipMemsetAsync(stats8, 0, (size_t)8 * 2 * HD * 4, stream);
    k_aggc<4, false><<<4 * ngrp, TB, 0, stream>>>(xb, rowptr, csru, dis,
                                                  nullptr, nullptr, nullptr, xa);
    k_mm2<FD, EPI_STATS><<<mmg2, TB, 0, stream>>>(xa, W1t, b1, dis, (unsigned short*)tbuf,
                                                  stats8, nullptr, nullptr, nullptr);
    k_affine<<<1, HD, 0, stream>>>(stats8, g1, be1, affa, affc);

    // layer 2: aggBN(t1') -> GEMM(+b2,relu,*dis, fused stats) -> t2'; affine
    k_aggc<8, true><<<8 * ngrp, TB, 0, stream>>>(tbuf, rowptr, csru, dis,
                                                 affa, affc, dsum, ah);
    k_mm2<HD, EPI_STATS><<<mmg2, TB, 0, stream>>>(ah, W2t, b2, dis, (unsigned short*)tbuf,
                                                  stats8, nullptr, nullptr, nullptr);
    k_affine<<<1, HD, 0, stream>>>(stats8, g2, be2, affa, affc);

    // layer 3: aggBN(t2') -> GEMM(+b3,relu) with boundary-aware fused mean-pool
    hipMemsetAsync(pooled, 0, (size_t)GN * HD * 4, stream);
    k_aggc<8, true><<<8 * ngrp, TB, 0, stream>>>(tbuf, rowptr, csru, dis,
                                                 affa, affc, dsum, ah);
    k_mm2<HD, EPI_POOL><<<mmg2, TB, 0, stream>>>(ah, W3t, b3, dis, nullptr,
                                                 nullptr, batch, gstart, pooled);

    // pool finalize
    k_poolfin<<<(GN * HD + TB - 1) / TB, TB, 0, stream>>>(pooled, gstart);

    // head
    k_head1<<<GN, TB, 0, stream>>>(pooled, actions, fW1, fb1, z1);
    k_headbn<<<1, TB, 0, stream>>>(z1, g3, be3);
    k_head2<<<GN, 128, 0, stream>>>(z1, fW2, fb2, z2);
    k_head3<<<1, 64, 0, stream>>>(z2, fW3, fb3, out);
}